// Round 15
// baseline (113.436 us; speedup 1.0000x reference)
//
#include <hip/hip_runtime.h>
#include <stdint.h>

// RelationTransform: out[i] = W[relation[i]] @ node_emb[i]
// N=32768, EMB=512, 16 relations, fp32 in/out.
// Prepass (4 launches): atomic-free block-histogram sort -> fused
// (gather X->bf16 sorted Xs + zero pads + convert W->bf16 Ws).
// GEMM gg15: A from Xs via gload_lds ring-3 (24KB LDS, verified swizzle,
// counted vmcnt); B = REGISTERS direct from L2 (W_r bf16 = 0.5MB, L2-fits:
// no LDS staging), 4 frags/wave loaded 2 tiles ahead. 128x128, 256 thr,
// 1088 blocks (~4/CU), ct-minor chunked XCD lids.

#define EMB 512
#define N_RELC 16
#define BM 128
#define BN 128
#define BK 32
#define NKT 16

typedef __attribute__((ext_vector_type(4))) float f32x4;
typedef __attribute__((ext_vector_type(8))) short bf16x8;

__device__ __forceinline__ unsigned short f2bf(float f) {
  unsigned int u = __float_as_uint(f);
  u += 0x7FFFu + ((u >> 16) & 1u);   // round-to-nearest-even
  return (unsigned short)(u >> 16);
}

__device__ __forceinline__ void gload_lds16(const void* g, void* l) {
  __builtin_amdgcn_global_load_lds(
      (const __attribute__((address_space(1))) unsigned int*)(uintptr_t)g,
      (__attribute__((address_space(3))) unsigned int*)(uintptr_t)l, 16, 0, 0);
}

// Atomic-free histogram: per-block LDS counts -> blockcnt[b][16] (plain
// stores, no pre-zero needed); pos[i] = within-block rank; ptok = -1 fill.
__global__ __launch_bounds__(256) void histo2(
    const int* __restrict__ rel, int* __restrict__ blockcnt,
    int* __restrict__ pos, int* __restrict__ ptok, int n, int padn, int nbh) {
  __shared__ int lcnt[N_RELC];
  const int tid = threadIdx.x;
  const int b = blockIdx.x;
  if (tid < N_RELC) lcnt[tid] = 0;
  __syncthreads();
  const int i = b * 256 + tid;
  if (i < padn) ptok[i] = -1;
  if (i < n) pos[i] = atomicAdd(&lcnt[rel[i]], 1);
  __syncthreads();
  if (b < nbh && tid < N_RELC) blockcnt[b * N_RELC + tid] = lcnt[tid];
}

// 1 block: cnt/pbase/tinfo + per-block scatter bases bbase[b][16].
__global__ __launch_bounds__(64) void prefix2(
    const int* __restrict__ blockcnt, int* __restrict__ cnt,
    int* __restrict__ pbase, int* __restrict__ bbase,
    int* __restrict__ tinfo, int nbh, int maxt) {
  __shared__ int sc[N_RELC];
  __shared__ int sb[N_RELC + 1];
  __shared__ int st[N_RELC + 1];
  const int tid = threadIdx.x;
  if (tid < N_RELC) {
    int s = 0;
    for (int b = 0; b < nbh; ++b) s += blockcnt[b * N_RELC + tid];
    sc[tid] = s;
  }
  __syncthreads();
  if (tid == 0) {
    int acc = 0, t = 0;
    for (int r = 0; r < N_RELC; ++r) {
      sb[r] = acc; st[r] = t;
      const int nt = (sc[r] + BM - 1) / BM;
      acc += nt * BM;
      t += nt;
    }
    sb[N_RELC] = acc; st[N_RELC] = t;
  }
  __syncthreads();
  if (tid < N_RELC) {
    cnt[tid] = sc[tid];
    int run = sb[tid];
    for (int b = 0; b < nbh; ++b) {
      bbase[b * N_RELC + tid] = run;
      run += blockcnt[b * N_RELC + tid];
    }
  }
  if (tid == 0) pbase[N_RELC] = sb[N_RELC];
  if (tid < N_RELC) pbase[tid] = sb[tid];
  for (int x = tid; x < maxt; x += 64) {
    int v = -1;
    #pragma unroll
    for (int r = 0; r < N_RELC; ++r)
      if (x >= st[r] && x < st[r + 1]) v = (r << 16) | (x - st[r]);
    tinfo[x] = v;
  }
}

// Fused prepass: [0,gb) gather X->Xs (+ptok), [gb,gb+16) zero pads,
// rest convert W->Ws.
__global__ __launch_bounds__(256) void prep_all2(
    const float* __restrict__ X, const float* __restrict__ W,
    const int* __restrict__ rel, const int* __restrict__ pos,
    const int* __restrict__ bbase, const int* __restrict__ pbase,
    const int* __restrict__ cnt, unsigned short* __restrict__ Xs,
    unsigned short* __restrict__ Ws, int* __restrict__ ptok,
    int n, int welems, int gb)
{
  const int b = blockIdx.x;
  if (b < gb) {                       // ---- gather+convert 4 token rows ----
    const int row = b * 4 + (threadIdx.x >> 6);
    const int lane = threadIdx.x & 63;
    if (row >= n) return;
    const int dst = bbase[(row >> 8) * N_RELC + rel[row]] + pos[row];
    if (lane == 0) ptok[dst] = row;
    const float* src = X + (size_t)row * EMB + lane * 8;
    f32x4 a = *reinterpret_cast<const f32x4*>(src);
    f32x4 c = *reinterpret_cast<const f32x4*>(src + 4);
    bf16x8 o;
    o[0] = f2bf(a[0]); o[1] = f2bf(a[1]); o[2] = f2bf(a[2]); o[3] = f2bf(a[3]);
    o[4] = f2bf(c[0]); o[5] = f2bf(c[1]); o[6] = f2bf(c[2]); o[7] = f2bf(c[3]);
    *reinterpret_cast<bf16x8*>(Xs + (size_t)dst * EMB + lane * 8) = o;
  } else if (b < gb + N_RELC) {       // ---- zero pad rows of relation r ----
    const int r = b - gb;
    const int start = pbase[r] + cnt[r];
    const int end = pbase[r + 1];
    const int nvec = (end - start) * (EMB / 8);
    unsigned short* p = Xs + (size_t)start * EMB;
    const bf16x8 z = {0, 0, 0, 0, 0, 0, 0, 0};
    for (int v = threadIdx.x; v < nvec; v += blockDim.x)
      *reinterpret_cast<bf16x8*>(p + (size_t)v * 8) = z;
  } else {                            // ---- convert W -> bf16 ----
    const size_t i = (((size_t)(b - gb - N_RELC)) * 256 + threadIdx.x) * 8;
    if (i >= (size_t)welems) return;
    f32x4 a = *reinterpret_cast<const f32x4*>(W + i);
    f32x4 c = *reinterpret_cast<const f32x4*>(W + i + 4);
    bf16x8 o;
    o[0] = f2bf(a[0]); o[1] = f2bf(a[1]); o[2] = f2bf(a[2]); o[3] = f2bf(a[3]);
    o[4] = f2bf(c[0]); o[5] = f2bf(c[1]); o[6] = f2bf(c[2]); o[7] = f2bf(c[3]);
    *reinterpret_cast<bf16x8*>(Ws + i) = o;
  }
}

// ---------------------------------------------------------------------------
// gg15. LDS: As ring-3 [128][32] bf16 (8KB each, 24KB). Rows 64B = 4x16B
// granules, phys = log ^ ((row>>1)&3) (verified 0-conflict); inverse on the
// global source. B: NO LDS - 4 bf16x8 frags per wave loaded straight from
// L2-resident Ws, 2 tiles ahead (parity reg sets, loaded AFTER compute so
// the set is free). ITER(t): ASTAGE(t+2)[2 vm]; vmcnt(VM)[A slab t + B(t)
// regs retired]; barrier; COMPUTE(t, set t&1); BLOAD(t+2)[4 vm]; lgkm(0);
// barrier. VM ladder (audited): 8 main, 6 @14, 0 @15.
// ---------------------------------------------------------------------------

#define ASTAGE(S, KT)                                                          \
  {                                                                            \
    const int kb_ = (KT) * BK;                                                 \
    gload_lds16(asrc0 + kb_, (char*)&As[S][0] + tid * 16);                     \
    gload_lds16(asrc1 + kb_, (char*)&As[S][0] + 4096 + tid * 16);              \
  }

#define BLOAD(P, KT)                                                           \
  {                                                                            \
    const unsigned short* bp_ = bptr + (KT) * BK;                              \
    b##P##0 = *reinterpret_cast<const bf16x8*>(bp_);                           \
    b##P##1 = *reinterpret_cast<const bf16x8*>(bp_ + 16 * EMB);                \
    b##P##2 = *reinterpret_cast<const bf16x8*>(bp_ + 32 * EMB);                \
    b##P##3 = *reinterpret_cast<const bf16x8*>(bp_ + 48 * EMB);                \
  }

#define COMPUTE(S, P)                                                          \
  {                                                                            \
    bf16x8 af[4];                                                              \
    _Pragma("unroll")                                                          \
    for (int m = 0; m < 4; ++m) {                                              \
      const int rr_ = wr * 64 + m * 16 + lrow;                                 \
      af[m] = *reinterpret_cast<const bf16x8*>(                                \
          (const char*)&As[S][0] + rr_ * 64 + ((gl ^ ((rr_ >> 1) & 3)) * 16)); \
    }                                                                          \
    __builtin_amdgcn_s_setprio(1);                                             \
    _Pragma("unroll")                                                          \
    for (int m = 0; m < 4; ++m) {                                              \
      acc[m][0] = __builtin_amdgcn_mfma_f32_16x16x32_bf16(af[m], b##P##0, acc[m][0], 0, 0, 0); \
      acc[m][1] = __builtin_amdgcn_mfma_f32_16x16x32_bf16(af[m], b##P##1, acc[m][1], 0, 0, 0); \
      acc[m][2] = __builtin_amdgcn_mfma_f32_16x16x32_bf16(af[m], b##P##2, acc[m][2], 0, 0, 0); \
      acc[m][3] = __builtin_amdgcn_mfma_f32_16x16x32_bf16(af[m], b##P##3, acc[m][3], 0, 0, 0); \
    }                                                                          \
    __builtin_amdgcn_s_setprio(0);                                             \
  }

#define ITER(T, VM)                                                            \
  {                                                                            \
    if ((T) + 2 < NKT) ASTAGE(((T) + 2) % 3, (T) + 2);                         \
    __builtin_amdgcn_sched_barrier(0);                                         \
    asm volatile("s_waitcnt vmcnt(" #VM ")" ::: "memory");                     \
    __builtin_amdgcn_s_barrier();                                              \
    __builtin_amdgcn_sched_barrier(0);                                         \
    if (((T) & 1) == 0) COMPUTE((T) % 3, e) else COMPUTE((T) % 3, o)           \
    if ((T) + 2 < NKT) {                                                       \
      if (((T) & 1) == 0) BLOAD(e, (T) + 2) else BLOAD(o, (T) + 2)             \
    }                                                                          \
    __builtin_amdgcn_sched_barrier(0);                                         \
    asm volatile("s_waitcnt lgkmcnt(0)" ::: "memory");                         \
    __builtin_amdgcn_s_barrier();                                              \
    __builtin_amdgcn_sched_barrier(0);                                         \
  }

__global__ __launch_bounds__(256, 4) void gg15(
    const unsigned short* __restrict__ Xs, const unsigned short* __restrict__ Ws,
    const int* __restrict__ pbase, const int* __restrict__ tinfo,
    const int* __restrict__ ptok, float* __restrict__ out)
{
  __shared__ unsigned short As[3][BM * BK];   // 3 x 8 KB = 24 KB

  // Chunked bijective XCD swizzle (gridDim.x % 8 == 0); lid = mtile*4 + ct.
  const int q = gridDim.x >> 3;
  const int lid = ((int)blockIdx.x & 7) * q + ((int)blockIdx.x >> 3);
  const int info = tinfo[lid >> 2];
  if (info < 0) return;
  const int r = info >> 16;
  const int mt = info & 0xFFFF;
  const int ct = lid & 3;
  const int prow0 = pbase[r] + mt * BM;

  const int tid = threadIdx.x;
  const int lane = tid & 63;
  const int wid = tid >> 6;
  const int wr = wid >> 1, wc = wid & 1;
  const int lrow = lane & 15;
  const int gl = lane >> 4;         // k-granule 0..3

  // A staging: shot0 rows 0-63 (row=tid>>2), shot1 rows 64-127; phys
  // granule tid&3 holds logical (tid&3)^((row>>1)&3) = (tid&3)^((tid>>3)&3).
  const int lg = (tid & 3) ^ ((tid >> 3) & 3);
  const unsigned short* asrc0 = Xs + (size_t)(prow0 + (tid >> 2)) * EMB + lg * 8;
  const unsigned short* asrc1 = asrc0 + (size_t)64 * EMB;

  // B fragment pointer (per lane, straight from L2-resident Ws).
  const unsigned short* bptr =
      Ws + ((size_t)r * EMB + (size_t)(ct * BN + wc * 64 + lrow)) * EMB + gl * 8;

  f32x4 acc[4][4];
  const f32x4 vzero = {0.f, 0.f, 0.f, 0.f};
  #pragma unroll
  for (int m = 0; m < 4; ++m)
    #pragma unroll
    for (int nn = 0; nn < 4; ++nn) acc[m][nn] = vzero;

  bf16x8 be0, be1, be2, be3, bo0, bo1, bo2, bo3;

  // Prologue: A slabs 0,1 + B tiles 0,1 in flight.
  ASTAGE(0, 0);
  __builtin_amdgcn_sched_barrier(0);
  BLOAD(e, 0)
  __builtin_amdgcn_sched_barrier(0);
  ASTAGE(1, 1);
  __builtin_amdgcn_sched_barrier(0);
  BLOAD(o, 1)
  __builtin_amdgcn_sched_barrier(0);

  ITER(0, 8)   ITER(1, 8)   ITER(2, 8)   ITER(3, 8)
  ITER(4, 8)   ITER(5, 8)   ITER(6, 8)   ITER(7, 8)
  ITER(8, 8)   ITER(9, 8)   ITER(10, 8)  ITER(11, 8)
  ITER(12, 8)  ITER(13, 8)  ITER(14, 6)  ITER(15, 0)

  // Epilogue: D mapping col=lane&15, row=(lane>>4)*4+reg
  #pragma unroll
  for (int m = 0; m < 4; ++m) {
    const int base = prow0 + wr * 64 + m * 16 + gl * 4;
    #pragma unroll
    for (int rg = 0; rg < 4; ++rg) {
      const int tok = ptok[base + rg];
      if (tok >= 0) {
        float* orow = out + (size_t)tok * EMB + ct * BN + wc * 64;
        #pragma unroll
        for (int nn = 0; nn < 4; ++nn)
          orow[nn * 16 + lrow] = acc[m][nn][rg];
      }
    }
  }
}

// Safety-net naive kernel (only if ws too small).
__global__ void naive_kernel(const float* __restrict__ X, const int* __restrict__ rel,
                             const float* __restrict__ W, float* __restrict__ out, int n) {
  int i = blockIdx.x;
  if (i >= n) return;
  int r = rel[i];
  const float* x = X + (size_t)i * EMB;
  const float* Wr = W + (size_t)r * EMB * EMB;
  for (int j = threadIdx.x; j < EMB; j += blockDim.x) {
    const float* w = Wr + (size_t)j * EMB;
    float s = 0.f;
    for (int k = 0; k < EMB; ++k) s += w[k] * x[k];
    out[(size_t)i * EMB + j] = s;
  }
}

extern "C" void kernel_launch(void* const* d_in, const int* in_sizes, int n_in,
                              void* d_out, int out_size, void* d_ws, size_t ws_size,
                              hipStream_t stream) {
  const float* X  = (const float*)d_in[0];
  const int* rel  = (const int*)d_in[1];
  const float* W  = (const float*)d_in[2];
  float* out      = (float*)d_out;
  const int n = in_sizes[1];
  const int welems = in_sizes[2];                 // n_rel * EMB * EMB
  const int padn = n + N_RELC * BM;
  const int nbh = (n + 255) / 256;                // histo blocks with tokens
  const int maxt = (n + BM - 1) / BM + N_RELC;
  const int maxtp = ((maxt + 1) / 2) * 2;         // grid = 4*maxtp -> %8==0

  const size_t ints = (size_t)64 + 32 + n + padn + maxtp + 2 * (size_t)nbh * N_RELC;
  const size_t offW = ((ints * sizeof(int) + 255) / 256) * 256;
  const size_t offX = offW + (((size_t)welems * 2 + 255) / 256) * 256;
  const size_t need = offX + (size_t)padn * EMB * 2;

  if (ws_size < need) {
    naive_kernel<<<n, 256, 0, stream>>>(X, rel, W, out, n);
    return;
  }

  int* cnt      = (int*)d_ws;            // 16 (+pad to 64)
  int* pbase    = cnt + 64;              // 17 (+pad to 32)
  int* pos      = pbase + 32;            // n
  int* ptok     = pos + n;               // padn
  int* tinfo    = ptok + padn;           // maxtp
  int* blockcnt = tinfo + maxtp;         // nbh*16
  int* bbase    = blockcnt + nbh * N_RELC;  // nbh*16
  unsigned short* Ws = (unsigned short*)((char*)d_ws + offW);
  unsigned short* Xs = (unsigned short*)((char*)d_ws + offX);

  const int gb = (n + 3) / 4;                       // gather blocks
  const int wb = (welems / 8 + 255) / 256;          // convert-W blocks
  const int gpad = (padn + 255) / 256;              // histo grid

  histo2<<<gpad, 256, 0, stream>>>(rel, blockcnt, pos, ptok, n, padn, nbh);
  prefix2<<<1, 64, 0, stream>>>(blockcnt, cnt, pbase, bbase, tinfo, nbh, maxtp);
  prep_all2<<<gb + N_RELC + wb, 256, 0, stream>>>(X, W, rel, pos, bbase, pbase,
                                                  cnt, Xs, Ws, ptok, n, welems, gb);

  gg15<<<4 * maxtp, 256, 0, stream>>>(Xs, Ws, pbase, tinfo, ptok, out);
}

// Round 17
// 82.612 us; speedup vs baseline: 1.3731x; 1.3731x over previous
//
#include <hip/hip_runtime.h>
#include <stdint.h>

// RelationTransform: out[i] = W[relation[i]] @ node_emb[i]
// N=32768, EMB=512, 16 relations, fp32 in/out.
// Prepass: histogram sort ONLY (~6us). No Xs, no Ws buffers.
// GEMM gg17 (gg16 +coverage fix): A = fused fp32 X reg-gather via ptok ->
// cvt -> swizzled ds_write (each of 256 thr stages TWO granules of one
// row: 128 rows covered). B = fp32 W via global_load_lds (linear dest,
// inverse-swizzled source col), cvt8 at fragment read. Ring-3 (72KB),
// counted vmcnt(16/8/0) audited for 8 VMEM/iter, ct-minor chunked XCD.

#define EMB 512
#define N_RELC 16
#define BM 128
#define BN 128
#define BK 32
#define NKT 16

typedef __attribute__((ext_vector_type(4))) float f32x4;
typedef __attribute__((ext_vector_type(8))) short bf16x8;

__device__ __forceinline__ unsigned short f2bf(float f) {
  unsigned int u = __float_as_uint(f);
  u += 0x7FFFu + ((u >> 16) & 1u);   // round-to-nearest-even
  return (unsigned short)(u >> 16);
}

__device__ __forceinline__ bf16x8 cvt8(f32x4 lo, f32x4 hi) {
  bf16x8 o;
  o[0] = (short)f2bf(lo[0]); o[1] = (short)f2bf(lo[1]);
  o[2] = (short)f2bf(lo[2]); o[3] = (short)f2bf(lo[3]);
  o[4] = (short)f2bf(hi[0]); o[5] = (short)f2bf(hi[1]);
  o[6] = (short)f2bf(hi[2]); o[7] = (short)f2bf(hi[3]);
  return o;
}

__device__ __forceinline__ void gload_lds16(const void* g, void* l) {
  __builtin_amdgcn_global_load_lds(
      (const __attribute__((address_space(1))) unsigned int*)(uintptr_t)g,
      (__attribute__((address_space(3))) unsigned int*)(uintptr_t)l, 16, 0, 0);
}

__global__ void init_counts(int* cnt) {
  if (threadIdx.x < 32) cnt[threadIdx.x] = 0;
}

// Per-block LDS histogram rank; also fills ptok[0..padn) with -1.
__global__ __launch_bounds__(256) void histo_rank_fill(
    const int* __restrict__ rel, int* cnt, int* pos, int* ptok,
    int n, int padn) {
  __shared__ int lcnt[N_RELC];
  __shared__ int lbase[N_RELC];
  const int tid = threadIdx.x;
  if (tid < N_RELC) lcnt[tid] = 0;
  __syncthreads();
  const int i = blockIdx.x * blockDim.x + tid;
  if (i < padn) ptok[i] = -1;
  int r = 0, myrank = 0;
  if (i < n) { r = rel[i]; myrank = atomicAdd(&lcnt[r], 1); }
  __syncthreads();
  if (tid < N_RELC) lbase[tid] = atomicAdd(&cnt[tid], lcnt[tid]);
  __syncthreads();
  if (i < n) pos[i] = lbase[r] + myrank;
}

// Padded segment bases + tile table (1 block, 64 threads).
__global__ void prefix_tiles64(const int* __restrict__ cnt, int* pbase,
                               int* tinfo, int maxt) {
  __shared__ int sb[N_RELC + 1];
  __shared__ int st[N_RELC + 1];
  if (threadIdx.x == 0) {
    int acc = 0, t = 0;
    for (int r = 0; r < N_RELC; ++r) {
      sb[r] = acc; st[r] = t;
      const int nt = (cnt[r] + BM - 1) / BM;
      acc += nt * BM;
      t += nt;
    }
    sb[N_RELC] = acc; st[N_RELC] = t;
  }
  __syncthreads();
  for (int i = threadIdx.x; i <= N_RELC; i += blockDim.x) pbase[i] = sb[i];
  for (int x = threadIdx.x; x < maxt; x += blockDim.x) {
    int v = -1;
    #pragma unroll
    for (int r = 0; r < N_RELC; ++r)
      if (x >= st[r] && x < st[r + 1]) v = (r << 16) | (x - st[r]);
    tinfo[x] = v;
  }
}

__global__ __launch_bounds__(256) void scatter_ptok(
    const int* __restrict__ rel, const int* __restrict__ pos,
    const int* __restrict__ pbase, int* __restrict__ ptok, int n) {
  const int i = blockIdx.x * blockDim.x + threadIdx.x;
  if (i < n) ptok[pbase[rel[i]] + pos[i]] = i;
}

// ---------------------------------------------------------------------------
// gg17. LDS ring-3: As bf16 [128][32] 8KB (64B rows = 4 granules, phys =
// log ^ ((row>>1)&3), verified 0-conflict). Bs fp32 [128][32] 16KB (128B
// rows = 8 x 16B slots, phys = log ^ (row&7); 2-way read aliasing = free).
// A path: thread owns row arow=tid>>1, granules g0=(tid&1)*2, g0+1.
//   Tile k: 4x f32x4 loads at ITER(k-2), cvt + 2 swizzled ds_write_b128
//   at ITER(k-1), consumed at ITER(k).  256 thr x 2 granules = 128 rows.
// B path: 4x gload_lds per slab from fp32 W (linear dest, source col
//   inverse-swizzled); cvt8 at fragment read inside COMPUTE.
// ITER(t): ALOAD(t+2)[4vm]; BSTAGE(t+2)[4vm]; vmcnt(VM)[B slab t done];
//   barrier; AWRITE(t+1); COMPUTE(t); lgkm(0); barrier.
// VM ladder (8 VMEM/iter, audited): 16 (t<=13), 8 (t=14), 0 (t=15).
// ---------------------------------------------------------------------------

#define ALOAD(P, KT)                                                           \
  {                                                                            \
    const float* ap_ = aptr + (KT) * BK;                                       \
    a##P##0 = *reinterpret_cast<const f32x4*>(ap_);                            \
    a##P##1 = *reinterpret_cast<const f32x4*>(ap_ + 4);                        \
    a##P##2 = *reinterpret_cast<const f32x4*>(ap_ + 8);                        \
    a##P##3 = *reinterpret_cast<const f32x4*>(ap_ + 12);                       \
  }

#define AWRITE(S, P)                                                           \
  {                                                                            \
    bf16x8 w0_ = cvt8(a##P##0, a##P##1);                                       \
    bf16x8 w1_ = cvt8(a##P##2, a##P##3);                                       \
    *reinterpret_cast<bf16x8*>((char*)&As[S][0] + awoff0) = w0_;               \
    *reinterpret_cast<bf16x8*>((char*)&As[S][0] + awoff1) = w1_;               \
  }

#define BSTAGE(S, KT)                                                          \
  {                                                                            \
    const int kb_ = (KT) * BK;                                                 \
    gload_lds16(bsrc0 + kb_, (char*)&Bs[S][0] + tid * 16);                     \
    gload_lds16(bsrc1 + kb_, (char*)&Bs[S][0] + 4096 + tid * 16);              \
    gload_lds16(bsrc2 + kb_, (char*)&Bs[S][0] + 8192 + tid * 16);              \
    gload_lds16(bsrc3 + kb_, (char*)&Bs[S][0] + 12288 + tid * 16);             \
  }

#define COMPUTE(S)                                                             \
  {                                                                            \
    bf16x8 af[4], bfr[4];                                                      \
    _Pragma("unroll")                                                          \
    for (int m = 0; m < 4; ++m) {                                              \
      const int rr_ = wr * 64 + m * 16 + lrow;                                 \
      af[m] = *reinterpret_cast<const bf16x8*>(                                \
          (const char*)&As[S][0] + rr_ * 64 + ((gl ^ ((rr_ >> 1) & 3)) * 16)); \
    }                                                                          \
    _Pragma("unroll")                                                          \
    for (int nn = 0; nn < 4; ++nn) {                                           \
      const int rw_ = wc * 64 + nn * 16 + lrow;                                \
      const char* bb_ = (const char*)&Bs[S][0] + rw_ * 128;                    \
      f32x4 lo = *reinterpret_cast<const f32x4*>(                              \
          bb_ + (((gl * 2) ^ (rw_ & 7)) * 16));                                \
      f32x4 hi = *reinterpret_cast<const f32x4*>(                              \
          bb_ + (((gl * 2 + 1) ^ (rw_ & 7)) * 16));                            \
      bfr[nn] = cvt8(lo, hi);                                                  \
    }                                                                          \
    __builtin_amdgcn_s_setprio(1);                                             \
    _Pragma("unroll")                                                          \
    for (int m = 0; m < 4; ++m)                                                \
      _Pragma("unroll")                                                        \
      for (int nn = 0; nn < 4; ++nn)                                           \
        acc[m][nn] = __builtin_amdgcn_mfma_f32_16x16x32_bf16(                  \
            af[m], bfr[nn], acc[m][nn], 0, 0, 0);                              \
    __builtin_amdgcn_s_setprio(0);                                             \
  }

#define ITER(T, VM)                                                            \
  {                                                                            \
    if ((T) + 2 < NKT) {                                                       \
      if (((T) & 1) == 0) ALOAD(e, (T) + 2) else ALOAD(o, (T) + 2)             \
      __builtin_amdgcn_sched_barrier(0);                                       \
      BSTAGE(((T) + 2) % 3, (T) + 2);                                          \
      __builtin_amdgcn_sched_barrier(0);                                       \
    }                                                                          \
    asm volatile("s_waitcnt vmcnt(" #VM ")" ::: "memory");                     \
    __builtin_amdgcn_s_barrier();                                              \
    __builtin_amdgcn_sched_barrier(0);                                         \
    if ((T) + 1 < NKT) {                                                       \
      if ((((T) + 1) & 1) == 0) AWRITE(((T) + 1) % 3, e)                       \
      else                      AWRITE(((T) + 1) % 3, o)                       \
    }                                                                          \
    COMPUTE((T) % 3);                                                          \
    asm volatile("s_waitcnt lgkmcnt(0)" ::: "memory");                         \
    __builtin_amdgcn_s_barrier();                                              \
    __builtin_amdgcn_sched_barrier(0);                                         \
  }

__global__ __launch_bounds__(256, 2) void gg17(
    const float* __restrict__ X, const float* __restrict__ W,
    const int* __restrict__ pbase, const int* __restrict__ tinfo,
    const int* __restrict__ ptok, float* __restrict__ out)
{
  __shared__ unsigned short As[3][BM * BK];   // 3 x 8 KB bf16
  __shared__ float Bs[3][BN * BK];            // 3 x 16 KB fp32 (72 KB total)

  // Chunked bijective XCD swizzle (gridDim.x % 8 == 0); lid = mtile*4 + ct
  // -> the 4 ct-siblings of an m-tile are contiguous in one XCD chunk.
  const int q = gridDim.x >> 3;
  const int lid = ((int)blockIdx.x & 7) * q + ((int)blockIdx.x >> 3);
  const int info = tinfo[lid >> 2];
  if (info < 0) return;
  const int r = info >> 16;
  const int mt = info & 0xFFFF;
  const int ct = lid & 3;
  const int prow0 = pbase[r] + mt * BM;

  const int tid = threadIdx.x;
  const int lane = tid & 63;
  const int wid = tid >> 6;
  const int wr = wid >> 1, wc = wid & 1;
  const int lrow = lane & 15;
  const int gl = lane >> 4;         // k-granule 0..3

  // A (fused): thread owns row arow = tid>>1, granules g0=(tid&1)*2, g0+1.
  const int arow = tid >> 1;
  const int g0 = (tid & 1) * 2;
  const int asw = (arow >> 1) & 3;
  const int awoff0 = arow * 64 + ((g0 ^ asw) * 16);
  const int awoff1 = arow * 64 + (((g0 + 1) ^ asw) * 16);
  int tokA = ptok[prow0 + arow];
  if (tokA < 0) tokA = 0;           // pad rows read token 0 (discarded)
  const float* aptr = X + (size_t)tokA * EMB + g0 * 8;

  // B (fp32 from W): shot s covers rows s*32 + (tid>>3); phys slot tid&7
  // holds logical (tid&7)^(row&7) -> inverse-swizzled source column.
  const int brow = tid >> 3;
  const int bcol = ((tid & 7) ^ (brow & 7)) * 4;
  const float* Wr = W + (size_t)r * EMB * EMB + (size_t)ct * BN * EMB;
  const float* bsrc0 = Wr + (size_t)(brow)       * EMB + bcol;
  const float* bsrc1 = Wr + (size_t)(brow + 32)  * EMB + bcol;
  const float* bsrc2 = Wr + (size_t)(brow + 64)  * EMB + bcol;
  const float* bsrc3 = Wr + (size_t)(brow + 96)  * EMB + bcol;

  f32x4 acc[4][4];
  const f32x4 vzero = {0.f, 0.f, 0.f, 0.f};
  #pragma unroll
  for (int m = 0; m < 4; ++m)
    #pragma unroll
    for (int nn = 0; nn < 4; ++nn) acc[m][nn] = vzero;

  f32x4 ae0, ae1, ae2, ae3, ao0, ao1, ao2, ao3;

  // Prologue: tiles 0,1 in flight (A regs + B slabs); slab0 A written.
  ALOAD(e, 0)
  __builtin_amdgcn_sched_barrier(0);
  BSTAGE(0, 0);
  __builtin_amdgcn_sched_barrier(0);
  ALOAD(o, 1)
  __builtin_amdgcn_sched_barrier(0);
  BSTAGE(1, 1);
  __builtin_amdgcn_sched_barrier(0);
  AWRITE(0, e)                      // compiler reg-dep waits tile-0 A loads
  asm volatile("s_waitcnt lgkmcnt(0)" ::: "memory");   // write done pre-barrier
  __builtin_amdgcn_sched_barrier(0);

  ITER(0, 16)  ITER(1, 16)  ITER(2, 16)  ITER(3, 16)
  ITER(4, 16)  ITER(5, 16)  ITER(6, 16)  ITER(7, 16)
  ITER(8, 16)  ITER(9, 16)  ITER(10, 16) ITER(11, 16)
  ITER(12, 16) ITER(13, 16) ITER(14, 8)  ITER(15, 0)

  // Epilogue: D mapping col=lane&15, row=(lane>>4)*4+reg
  #pragma unroll
  for (int m = 0; m < 4; ++m) {
    const int base = prow0 + wr * 64 + m * 16 + gl * 4;
    #pragma unroll
    for (int rg = 0; rg < 4; ++rg) {
      const int tok = ptok[base + rg];
      if (tok >= 0) {
        float* orow = out + (size_t)tok * EMB + ct * BN + wc * 64;
        #pragma unroll
        for (int nn = 0; nn < 4; ++nn)
          orow[nn * 16 + lrow] = acc[m][nn][rg];
      }
    }
  }
}

// Safety-net naive kernel (only if ws too small).
__global__ void naive_kernel(const float* __restrict__ X, const int* __restrict__ rel,
                             const float* __restrict__ W, float* __restrict__ out, int n) {
  int i = blockIdx.x;
  if (i >= n) return;
  int r = rel[i];
  const float* x = X + (size_t)i * EMB;
  const float* Wr = W + (size_t)r * EMB * EMB;
  for (int j = threadIdx.x; j < EMB; j += blockDim.x) {
    const float* w = Wr + (size_t)j * EMB;
    float s = 0.f;
    for (int k = 0; k < EMB; ++k) s += w[k] * x[k];
    out[(size_t)i * EMB + j] = s;
  }
}

extern "C" void kernel_launch(void* const* d_in, const int* in_sizes, int n_in,
                              void* d_out, int out_size, void* d_ws, size_t ws_size,
                              hipStream_t stream) {
  const float* X  = (const float*)d_in[0];
  const int* rel  = (const int*)d_in[1];
  const float* W  = (const float*)d_in[2];
  float* out      = (float*)d_out;
  const int n = in_sizes[1];
  const int padn = n + N_RELC * BM;
  const int maxt = (n + BM - 1) / BM + N_RELC;
  const int maxtp = ((maxt + 1) / 2) * 2;         // grid = 4*maxtp -> %8==0

  const size_t need = (size_t)(64 + 32 + n + padn + maxtp) * sizeof(int);

  if (ws_size < need) {
    naive_kernel<<<n, 256, 0, stream>>>(X, rel, W, out, n);
    return;
  }

  int* cnt   = (int*)d_ws;       // 16 (+pad to 64)
  int* pbase = cnt + 64;         // 17 (+pad to 32)
  int* pos   = pbase + 32;       // n
  int* ptok  = pos + n;          // padn
  int* tinfo = ptok + padn;      // maxtp

  init_counts<<<1, 32, 0, stream>>>(cnt);
  histo_rank_fill<<<(padn + 255) / 256, 256, 0, stream>>>(rel, cnt, pos, ptok, n, padn);
  prefix_tiles64<<<1, 64, 0, stream>>>(cnt, pbase, tinfo, maxtp);
  scatter_ptok<<<(n + 255) / 256, 256, 0, stream>>>(rel, pos, pbase, ptok, n);

  gg17<<<4 * maxtp, 256, 0, stream>>>(X, W, pbase, tinfo, ptok, out);
}